// Round 4
// baseline (173.289 us; speedup 1.0000x reference)
//
#include <hip/hip_runtime.h>

#define SPK 1024
#define UTT 64
#define DIM 256
#define EPSV 1e-5f
#define NROW (SPK * UTT)
#define NSL 8            // partial slices: (col-half h) x (wave n-subtile)
#define LOG2E 1.44269504f

typedef __attribute__((ext_vector_type(4))) float f32x4;    // MFMA accumulator
typedef __attribute__((ext_vector_type(2))) long long2v;    // 16 B = 2 fp8 ktile frags

#define EXP2(x) __builtin_amdgcn_exp2f(x)     // bare v_exp_f32, no libm guards

// pack 4 floats -> 4 fp8 e4m3 bytes
__device__ __forceinline__ int pk_fp8(float a, float b, float c, float d) {
    int v = __builtin_amdgcn_cvt_pk_fp8_f32(a, b, 0, false);   // bytes 0,1
    return  __builtin_amdgcn_cvt_pk_fp8_f32(c, d, v, true);    // bytes 2,3
}

// MFMA-fragment byte order for a 256-byte fp8 row/column:
// unit (r,quad) (16 B) = k-bytes [2r*32+quad*8 .. +8] ++ [(2r+1)*32+quad*8 .. +8].
// fragIdx maps original int-group g (bytes g*4..+4) -> stored int index.
__device__ __forceinline__ int fragIdx(int g) {
    return ((g >> 4) * 4 + ((g & 7) >> 1)) * 4 + ((g >> 3) & 1) * 2 + (g & 1);
}

// K1: one block (256 thr) per speaker; x read ONCE, fully coalesced, kept in
// registers (xv[16] float4/thread). Pass A: col sums -> csum (LDS), ||csum||^2,
// cincl8 (fp8 x16, fragment order). Pass B (no re-read): per-row ||x||^2 and
// x.csum via per-thread 4-col partials + 6-level wave butterfly; quantize en8
// (fp8 x16, fragment order, round-0 verified layout) and fp32 texcl.
__global__ __launch_bounds__(256, 4)
void k_prep(const float* __restrict__ x,
            unsigned char* __restrict__ cincl8,
            unsigned char* __restrict__ en8,
            float* __restrict__ texcl,
            const float* __restrict__ wp, const float* __restrict__ bp) {
    __shared__ float4 sc4[256];
    __shared__ float4 csq[64];
    __shared__ float sccs;
    int s = blockIdx.x, tid = threadIdx.x;
    int dq = tid & 63, ug = tid >> 6;            // col-quad, row-group
    const float4* x4 = (const float4*)(x + (size_t)s * UTT * DIM);

    // pass A: coalesced load (1KB/wave-instr), col sums over 64 rows
    float4 xv[16];
    float4 p = {0.f, 0.f, 0.f, 0.f};
#pragma unroll
    for (int i = 0; i < 16; ++i) {
        float4 v = x4[(ug * 16 + i) * 64 + dq];
        xv[i] = v;
        p.x += v.x; p.y += v.y; p.z += v.z; p.w += v.w;
    }
    sc4[tid] = p;
    __syncthreads();
    if (tid < 64) {
        float4 a = sc4[dq], b2 = sc4[64 + dq], c = sc4[128 + dq], d = sc4[192 + dq];
        float4 cs = {a.x + b2.x + c.x + d.x, a.y + b2.y + c.y + d.y,
                     a.z + b2.z + c.z + d.z, a.w + b2.w + c.w + d.w};
        csq[dq] = cs;                            // csum stays in LDS (no global)
        float s2 = cs.x * cs.x + cs.y * cs.y + cs.z * cs.z + cs.w * cs.w;
#pragma unroll
        for (int o = 1; o < 64; o <<= 1) s2 += __shfl_xor(s2, o);
        // c_incl = csum/(||csum|| + U*eps), quantized x16 into e4m3
        float inv = 16.f / (sqrtf(s2) + UTT * EPSV);
        ((int*)cincl8)[s * 64 + fragIdx(dq)] =
            pk_fp8(cs.x * inv, cs.y * inv, cs.z * inv, cs.w * inv);
        if (tid == 0) sccs = s2;
    }
    __syncthreads();
    float scc = sccs;
    float4 cv = csq[dq];
    float w = wp[0], b = bp[0];

    // pass B: per-row partials over this thread's 4 cols, butterfly all-reduce
    float sxl[16], scl[16];
#pragma unroll
    for (int i = 0; i < 16; ++i) {
        float4 v = xv[i];
        sxl[i] = v.x * v.x + v.y * v.y + v.z * v.z + v.w * v.w;
        scl[i] = v.x * cv.x + v.y * cv.y + v.z * cv.z + v.w * cv.w;
    }
#pragma unroll
    for (int o = 1; o < 64; o <<= 1)
#pragma unroll
        for (int i = 0; i < 16; ++i) {
            sxl[i] += __shfl_xor(sxl[i], o);
            scl[i] += __shfl_xor(scl[i], o);
        }
    // quantize rows into en8 (stored int index = fragIdx(col-group))
    int fi = fragIdx(dq);
#pragma unroll
    for (int i = 0; i < 16; ++i) {
        float inv = 16.f / (sqrtf(sxl[i]) + EPSV);
        ((int*)(en8 + (size_t)(s * UTT + ug * 16 + i) * DIM))[fi] =
            pk_fp8(xv[i].x * inv, xv[i].y * inv, xv[i].z * inv, xv[i].w * inv);
    }
    if (dq == 0) {
        // sim_excl = x.(csum-x) / ((||x||+eps)(||csum-x||+63eps))  (fp32 exact)
#pragma unroll
        for (int i = 0; i < 16; ++i) {
            float nx = sqrtf(sxl[i]);
            float num = scl[i] - sxl[i];
            float e2 = fmaxf(scc - 2.f * scl[i] + sxl[i], 0.f);
            float sim = num / ((nx + EPSV) * (sqrtf(e2) + (UTT - 1) * EPSV));
            texcl[s * UTT + ug * 16 + i] = fmaf(sim, w, b);
        }
    }
}

// K2: pure streaming fp8 matmul + exp accumulation. Block = (speaker, col
// half): 2048 blocks queue ~8 deep per CU so af-load latency of later blocks
// hides under MFMA of earlier ones. Wave holds all 4 m-tiles of its speaker
// (af from en8, L3-hot, 16 b128 gathers) and one 16-col n-subtile per step; B
// fragments come DIRECTLY from L2-resident cincl8 with 1-step prefetch.
// 8 independent 4-deep MFMA chains. Zero LDS, zero barriers.
// NOTE: the 4 waves cover the SAME rows over different cols -> each
// (h, wave) writes its OWN partial slice (race fix for round 3).
__global__ __launch_bounds__(256, 2)
void k_main(const unsigned char* __restrict__ en8,
            const unsigned char* __restrict__ cincl8,
            float* __restrict__ partial,
            const float* __restrict__ wp, const float* __restrict__ bp) {
    int tid = threadIdx.x, wave = tid >> 6, lane = tid & 63;
    int quad = lane >> 4, lx = lane & 15;
    int bid = blockIdx.x;
    int s = bid & (SPK - 1), h = bid >> 10;      // speaker, col-half
    float w = wp[0], b = bp[0];
    float M  = fabsf(w) * 1.0625f + b;           // >= any logit (|sim| <= ~1)
    float wl = w * (LOG2E / 256.f);              // undo x16*x16 quant scale
    float bl = (b - M) * LOG2E;                  // exp(v-M) = exp2(acc*wl + bl)

    // A fragments: af[mt][r] = ktiles (2r, 2r+1) of row mt*16+lx
    const unsigned char* abase = en8 + (size_t)s * UTT * DIM;
    long2v af[4][4];
#pragma unroll
    for (int mt = 0; mt < 4; ++mt)
#pragma unroll
        for (int r = 0; r < 4; ++r)
            af[mt][r] = *(const long2v*)(abase + (mt * 16 + lx) * DIM + (r * 4 + quad) * 16);

    float l[16];
#pragma unroll
    for (int i = 0; i < 16; ++i) l[i] = 0.f;
    int t_d = s >> 6, w_d = (s >> 4) & 3, lx_d = s & 15;
    const unsigned char* bp_ = cincl8 + (size_t)(wave * 16 + lx) * DIM + quad * 16;

    long2v bfc[4], bfn[4];
    int t0 = h * 8;
#pragma unroll
    for (int r = 0; r < 4; ++r)
        bfc[r] = *(const long2v*)(bp_ + (size_t)(t0 * 64) * DIM + r * 64);

    for (int t = t0; t < t0 + 8; ++t) {
        const unsigned char* bn = bp_ + (size_t)(((t + 1) & 15) * 64) * DIM;
#pragma unroll
        for (int r = 0; r < 4; ++r)              // prefetch next step's B
            bfn[r] = *(const long2v*)(bn + r * 64);
        f32x4 aA[4] = {{0.f,0.f,0.f,0.f},{0.f,0.f,0.f,0.f},
                       {0.f,0.f,0.f,0.f},{0.f,0.f,0.f,0.f}};
        f32x4 aB[4] = {{0.f,0.f,0.f,0.f},{0.f,0.f,0.f,0.f},
                       {0.f,0.f,0.f,0.f},{0.f,0.f,0.f,0.f}};
#pragma unroll
        for (int r = 0; r < 2; ++r) {            // 8 interleaved 4-deep chains
#pragma unroll
            for (int mt = 0; mt < 4; ++mt) {
                aA[mt] = __builtin_amdgcn_mfma_f32_16x16x32_fp8_fp8(af[mt][r].x,   bfc[r].x,   aA[mt], 0, 0, 0);
                aB[mt] = __builtin_amdgcn_mfma_f32_16x16x32_fp8_fp8(af[mt][r+2].x, bfc[r+2].x, aB[mt], 0, 0, 0);
            }
#pragma unroll
            for (int mt = 0; mt < 4; ++mt) {
                aA[mt] = __builtin_amdgcn_mfma_f32_16x16x32_fp8_fp8(af[mt][r].y,   bfc[r].y,   aA[mt], 0, 0, 0);
                aB[mt] = __builtin_amdgcn_mfma_f32_16x16x32_fp8_fp8(af[mt][r+2].y, bfc[r+2].y, aB[mt], 0, 0, 0);
            }
        }
#pragma unroll
        for (int mt = 0; mt < 4; ++mt)
#pragma unroll
            for (int i = 0; i < 4; ++i)
                l[mt * 4 + i] += EXP2(fmaf(aA[mt][i] + aB[mt][i], wl, bl));
        if (t == t_d && wave == w_d) {           // wave-uniform: undo diag col
#pragma unroll
            for (int mt = 0; mt < 4; ++mt)
#pragma unroll
                for (int i = 0; i < 4; ++i) {
                    float e = EXP2(fmaf(aA[mt][i] + aB[mt][i], wl, bl));
                    if (lx == lx_d) l[mt * 4 + i] -= e;
                }
        }
#pragma unroll
        for (int r = 0; r < 4; ++r) bfc[r] = bfn[r];
    }

    // reduce over the 16 col-lanes; rows live at (mt, quad, i)
#pragma unroll
    for (int o = 1; o < 16; o <<= 1)
#pragma unroll
        for (int i = 0; i < 16; ++i) l[i] += __shfl_xor(l[i], o);
    if (lx == 0)
#pragma unroll
        for (int mt = 0; mt < 4; ++mt)
#pragma unroll
            for (int i = 0; i < 4; ++i)
                partial[(size_t)(h * 4 + wave) * NROW + (size_t)s * UTT
                        + mt * 16 + quad * 4 + i] = l[mt * 4 + i];
}

// K3: combine the 8 (half, wave) partials per row, logsumexp, mean-reduce.
__global__ __launch_bounds__(256)
void k_final(const float* __restrict__ partial, const float* __restrict__ texcl,
             const float* __restrict__ wp, const float* __restrict__ bp,
             float* __restrict__ out) {
    int row = blockIdx.x * 256 + threadIdx.x;
    float w = wp[0], b = bp[0];
    float M = fabsf(w) * 1.0625f + b;
    float t = 0.f;
#pragma unroll
    for (int sl = 0; sl < NSL; ++sl) t += partial[(size_t)sl * NROW + row];
    float tex = texcl[row];
    float c = (M + __logf(t + EXP2((tex - M) * LOG2E))) - tex;   // lse - target
#pragma unroll
    for (int o = 1; o < 64; o <<= 1) c += __shfl_xor(c, o);
    __shared__ float red[4];
    if ((threadIdx.x & 63) == 0) red[threadIdx.x >> 6] = c;
    __syncthreads();
    if (threadIdx.x == 0)
        atomicAdd(out, (red[0] + red[1] + red[2] + red[3]) * (1.f / NROW));
}

extern "C" void kernel_launch(void* const* d_in, const int* in_sizes, int n_in,
                              void* d_out, int out_size, void* d_ws, size_t ws_size,
                              hipStream_t stream) {
    const float* x  = (const float*)d_in[0];
    const float* wp = (const float*)d_in[1];
    const float* bp = (const float*)d_in[2];
    char* ws = (char*)d_ws;
    unsigned char* cincl8 = (unsigned char*)ws;                     // @0,    256 KB
    float* texcl          = (float*)(ws + (1u << 19));              // @512K, 256 KB
    float* partial        = (float*)(ws + (1u << 20));              // @1M,   2 MB
    unsigned char* en8    = (unsigned char*)(ws + (4u << 20));      // @4M,   16 MB
    float* out = (float*)d_out;

    hipMemsetAsync(d_out, 0, sizeof(float), stream);
    k_prep <<<SPK, 256, 0, stream>>>(x, cincl8, en8, texcl, wp, bp);
    k_main <<<2 * SPK, 256, 0, stream>>>(en8, cincl8, partial, wp, bp);
    k_final<<<NROW / 256, 256, 0, stream>>>(partial, texcl, wp, bp, out);
}

// Round 6
// 157.307 us; speedup vs baseline: 1.1016x; 1.1016x over previous
//
#include <hip/hip_runtime.h>

#define SPK 1024
#define UTT 64
#define DIM 256
#define EPSV 1e-5f
#define NROW (SPK * UTT)
#define NSL 16           // partial slices: (col-group g) x (wave) -- RACE KEY
#define LOG2E 1.44269504f

typedef __attribute__((ext_vector_type(4))) float f32x4;    // MFMA accumulator
typedef __attribute__((ext_vector_type(2))) long long2v;    // 16 B = 2 fp8 ktile frags

#define EXP2(x) __builtin_amdgcn_exp2f(x)     // bare v_exp_f32, no libm guards

// pack 4 floats -> 4 fp8 e4m3 bytes
__device__ __forceinline__ int pk_fp8(float a, float b, float c, float d) {
    int v = __builtin_amdgcn_cvt_pk_fp8_f32(a, b, 0, false);   // bytes 0,1
    return  __builtin_amdgcn_cvt_pk_fp8_f32(c, d, v, true);    // bytes 2,3
}

// MFMA-fragment byte order for a 256-byte fp8 row/column:
// unit (r,quad) (16 B) = k-bytes [2r*32+quad*8 .. +8] ++ [(2r+1)*32+quad*8 .. +8].
// fragIdx maps original int-group g (bytes g*4..+4) -> stored int index.
__device__ __forceinline__ int fragIdx(int g) {
    return ((g >> 4) * 4 + ((g & 7) >> 1)) * 4 + ((g >> 3) & 1) * 2 + (g & 1);
}

// K1: one block (256 thr) per speaker; x read ONCE, fully coalesced, kept in
// registers (xv[16] float4/thread). Pass A: col sums -> csum (LDS), ||csum||^2,
// cincl8 (fp8 x16, fragment order). Pass B (no re-read): per-row ||x||^2 and
// x.csum via per-thread 4-col partials + 6-level wave butterfly; quantize en8
// (fp8 x16, fragment order) and fp32 texcl.
// launch_bounds (256,2): 256-VGPR cap -- live-set ~140 VGPRs MUST NOT SPILL
// (a 128 cap spills xv[16] and wrecks this kernel).
__global__ __launch_bounds__(256, 2)
void k_prep(const float* __restrict__ x,
            unsigned char* __restrict__ cincl8,
            unsigned char* __restrict__ en8,
            float* __restrict__ texcl,
            const float* __restrict__ wp, const float* __restrict__ bp) {
    __shared__ float4 sc4[256];
    __shared__ float4 csq[64];
    __shared__ float sccs;
    int s = blockIdx.x, tid = threadIdx.x;
    int dq = tid & 63, ug = tid >> 6;            // col-quad, row-group
    const float4* x4 = (const float4*)(x + (size_t)s * UTT * DIM);

    // pass A: coalesced load (1KB/wave-instr), col sums over 64 rows
    float4 xv[16];
    float4 p = {0.f, 0.f, 0.f, 0.f};
#pragma unroll
    for (int i = 0; i < 16; ++i) {
        float4 v = x4[(ug * 16 + i) * 64 + dq];
        xv[i] = v;
        p.x += v.x; p.y += v.y; p.z += v.z; p.w += v.w;
    }
    sc4[tid] = p;
    __syncthreads();
    if (tid < 64) {
        float4 a = sc4[dq], b2 = sc4[64 + dq], c = sc4[128 + dq], d = sc4[192 + dq];
        float4 cs = {a.x + b2.x + c.x + d.x, a.y + b2.y + c.y + d.y,
                     a.z + b2.z + c.z + d.z, a.w + b2.w + c.w + d.w};
        csq[dq] = cs;                            // csum stays in LDS (no global)
        float s2 = cs.x * cs.x + cs.y * cs.y + cs.z * cs.z + cs.w * cs.w;
#pragma unroll
        for (int o = 1; o < 64; o <<= 1) s2 += __shfl_xor(s2, o);
        // c_incl = csum/(||csum|| + U*eps), quantized x16 into e4m3
        float inv = 16.f / (sqrtf(s2) + UTT * EPSV);
        ((int*)cincl8)[s * 64 + fragIdx(dq)] =
            pk_fp8(cs.x * inv, cs.y * inv, cs.z * inv, cs.w * inv);
        if (tid == 0) sccs = s2;
    }
    __syncthreads();
    float scc = sccs;
    float4 cv = csq[dq];
    float w = wp[0], b = bp[0];

    // pass B: per-row partials over this thread's 4 cols, butterfly all-reduce
    float sxl[16], scl[16];
#pragma unroll
    for (int i = 0; i < 16; ++i) {
        float4 v = xv[i];
        sxl[i] = v.x * v.x + v.y * v.y + v.z * v.z + v.w * v.w;
        scl[i] = v.x * cv.x + v.y * cv.y + v.z * cv.z + v.w * cv.w;
    }
#pragma unroll
    for (int o = 1; o < 64; o <<= 1)
#pragma unroll
        for (int i = 0; i < 16; ++i) {
            sxl[i] += __shfl_xor(sxl[i], o);
            scl[i] += __shfl_xor(scl[i], o);
        }
    // quantize rows into en8 (stored int index = fragIdx(col-group))
    int fi = fragIdx(dq);
#pragma unroll
    for (int i = 0; i < 16; ++i) {
        float inv = 16.f / (sqrtf(sxl[i]) + EPSV);
        ((int*)(en8 + (size_t)(s * UTT + ug * 16 + i) * DIM))[fi] =
            pk_fp8(xv[i].x * inv, xv[i].y * inv, xv[i].z * inv, xv[i].w * inv);
    }
    if (dq == 0) {
        // sim_excl = x.(csum-x) / ((||x||+eps)(||csum-x||+63eps))  (fp32 exact)
#pragma unroll
        for (int i = 0; i < 16; ++i) {
            float nx = sqrtf(sxl[i]);
            float num = scl[i] - sxl[i];
            float e2 = fmaxf(scc - 2.f * scl[i] + sxl[i], 0.f);
            float sim = num / ((nx + EPSV) * (sqrtf(e2) + (UTT - 1) * EPSV));
            texcl[s * UTT + ug * 16 + i] = fmaf(sim, w, b);
        }
    }
}

// K2: B-stationary fp8 matmul + exp accumulation. Wave = 64 FIXED cols
// (4 n-tiles, bf[4][4] = 64 VGPR loaded once); block = 4 waves = 256 cols;
// block streams 4 speakers x 4 m-tiles of A from en8 (af[4] = 16 VGPR per
// step, 4 b128 loads : 32 MFMAs, L1-hot across the 4 waves). Live-set
// ~115 VGPR fits the (256,4)/128 cap -> 16 waves/CU, no spills. Zero LDS,
// zero barriers.
// RACE KEY: concurrent writers of one output row are distinguished by
// (g, wave) -- the 4 waves of a block cover the SAME rows over different
// cols -> each (g*4+wave) writes its OWN partial slice (round-3/5 lesson).
__global__ __launch_bounds__(256, 4)
void k_main(const unsigned char* __restrict__ en8,
            const unsigned char* __restrict__ cincl8,
            float* __restrict__ partial,
            const float* __restrict__ wp, const float* __restrict__ bp) {
    int tid = threadIdx.x, wave = tid >> 6, lane = tid & 63;
    int quad = lane >> 4, lx = lane & 15;
    int bid = blockIdx.x;
    int g = bid & 3;                             // col-group (256 cols)
    int c = bid >> 2;                            // speaker chunk (4 speakers)
    float w = wp[0], b = bp[0];
    float M  = fabsf(w) * 1.0625f + b;           // >= any logit (|sim| <= ~1)
    float wl = w * (LOG2E / 256.f);              // undo x16*x16 quant scale
    float bl = (b - M) * LOG2E;                  // exp(v-M) = exp2(acc*wl + bl)

    int col0 = g * 256 + wave * 64;              // wave's 64 cols
    long2v bf[4][4];                             // bf[nt][r]: col col0+nt*16+lx
#pragma unroll
    for (int nt = 0; nt < 4; ++nt)
#pragma unroll
        for (int r = 0; r < 4; ++r)
            bf[nt][r] = *(const long2v*)(cincl8 +
                (size_t)(col0 + nt * 16 + lx) * DIM + (r * 4 + quad) * 16);

    for (int sp = 0; sp < 4; ++sp) {
        int s = c * 4 + sp;
        const unsigned char* abase = en8 + (size_t)s * UTT * DIM;
        // diag col s lives in this wave iff its 64-col window covers it
        bool dgw = ((s >> 8) == g) && (((s >> 6) & 3) == wave);
        int nt_d = (s >> 4) & 3, lx_d = s & 15;
        for (int mt = 0; mt < 4; ++mt) {
            long2v af[4];                        // rows mt*16+lx, ktiles (2r,2r+1)
#pragma unroll
            for (int r = 0; r < 4; ++r)
                af[r] = *(const long2v*)(abase + (mt * 16 + lx) * DIM + (r * 4 + quad) * 16);
            f32x4 acc[4] = {{0.f,0.f,0.f,0.f},{0.f,0.f,0.f,0.f},
                            {0.f,0.f,0.f,0.f},{0.f,0.f,0.f,0.f}};
#pragma unroll
            for (int r = 0; r < 4; ++r) {        // 4 independent 8-deep chains
#pragma unroll
                for (int nt = 0; nt < 4; ++nt)
                    acc[nt] = __builtin_amdgcn_mfma_f32_16x16x32_fp8_fp8(af[r].x, bf[nt][r].x, acc[nt], 0, 0, 0);
#pragma unroll
                for (int nt = 0; nt < 4; ++nt)
                    acc[nt] = __builtin_amdgcn_mfma_f32_16x16x32_fp8_fp8(af[r].y, bf[nt][r].y, acc[nt], 0, 0, 0);
            }
            float ps[4] = {0.f, 0.f, 0.f, 0.f};  // row-sums over this wave's cols
#pragma unroll
            for (int nt = 0; nt < 4; ++nt) {
                bool dgn = dgw && (nt == nt_d);  // wave-uniform
#pragma unroll
                for (int i = 0; i < 4; ++i) {
                    float e = EXP2(fmaf(acc[nt][i], wl, bl));
                    if (!(dgn && lx == lx_d)) ps[i] += e;   // skip diag col
                }
            }
#pragma unroll
            for (int o = 1; o < 16; o <<= 1)     // reduce over 16 col-lanes
#pragma unroll
                for (int i = 0; i < 4; ++i) ps[i] += __shfl_xor(ps[i], o);
            if (lx == 0)
#pragma unroll
                for (int i = 0; i < 4; ++i)
                    partial[(size_t)(g * 4 + wave) * NROW + (size_t)s * UTT
                            + mt * 16 + quad * 4 + i] = ps[i];
        }
    }
}

// K3: combine the 16 (col-group, wave) partials per row, logsumexp, mean.
__global__ __launch_bounds__(256)
void k_final(const float* __restrict__ partial, const float* __restrict__ texcl,
             const float* __restrict__ wp, const float* __restrict__ bp,
             float* __restrict__ out) {
    int row = blockIdx.x * 256 + threadIdx.x;
    float w = wp[0], b = bp[0];
    float M = fabsf(w) * 1.0625f + b;
    float t = 0.f;
#pragma unroll
    for (int sl = 0; sl < NSL; ++sl) t += partial[(size_t)sl * NROW + row];
    float tex = texcl[row];
    float c = (M + __logf(t + EXP2((tex - M) * LOG2E))) - tex;   // lse - target
#pragma unroll
    for (int o = 1; o < 64; o <<= 1) c += __shfl_xor(c, o);
    __shared__ float red[4];
    if ((threadIdx.x & 63) == 0) red[threadIdx.x >> 6] = c;
    __syncthreads();
    if (threadIdx.x == 0)
        atomicAdd(out, (red[0] + red[1] + red[2] + red[3]) * (1.f / NROW));
}

extern "C" void kernel_launch(void* const* d_in, const int* in_sizes, int n_in,
                              void* d_out, int out_size, void* d_ws, size_t ws_size,
                              hipStream_t stream) {
    const float* x  = (const float*)d_in[0];
    const float* wp = (const float*)d_in[1];
    const float* bp = (const float*)d_in[2];
    char* ws = (char*)d_ws;
    unsigned char* cincl8 = (unsigned char*)ws;                     // @0,    256 KB
    float* texcl          = (float*)(ws + (1u << 19));              // @512K, 256 KB
    float* partial        = (float*)(ws + (1u << 20));              // @1M,   4 MB
    unsigned char* en8    = (unsigned char*)(ws + (8u << 20));      // @8M,   16 MB
    float* out = (float*)d_out;

    hipMemsetAsync(d_out, 0, sizeof(float), stream);
    k_prep <<<SPK, 256, 0, stream>>>(x, cincl8, en8, texcl, wp, bp);
    k_main <<<4 * (SPK / 4), 256, 0, stream>>>(en8, cincl8, partial, wp, bp);
    k_final<<<NROW / 256, 256, 0, stream>>>(partial, texcl, wp, bp, out);
}